// Round 9
// baseline (131.007 us; speedup 1.0000x reference)
//
#include <hip/hip_runtime.h>
#include <hip/hip_bf16.h>

#define NATC 10000
#define NATP 10016          // padded atom count for MFMA m-tiles
#define NNC 32
#define RSNC 16
#define THETANC 8
#define NEMBC 4
#define FEATC 576

typedef __attribute__((ext_vector_type(8))) short short8;  // 8 bf16 (4 VGPRs)
typedef __attribute__((ext_vector_type(4))) float f32x4;

static __device__ __forceinline__ short f2bf(float x) {
    union { __hip_bfloat16 h; short s; } u;
    u.h = __float2bfloat16(x);
    return u.s;
}

// Hardware paired f32->bf16 convert (RNE, same rounding as __float2bfloat16;
// bit-agreement proven R1<->R2, both absmax 0.0). Operands are FRESH scalars
// (the R3/R4 miscompile class was hoisted ext-vector tuples x pk_fma chains;
// cvt_pk on scalars hoisted across the theta loop is R2's proven pattern).
static __device__ __forceinline__ int cvt_pk_bf16(float lo, float hi) {
    int r;
    asm("v_cvt_pk_bf16_f32 %0, %1, %2" : "=v"(r) : "v"(lo), "v"(hi));
    return r;
}

// HW trig: v_sin/v_cos take REVOLUTIONS; reduce exactly via floor.
static __device__ __forceinline__ float hw_cos_rev(float rev) {
    return __builtin_amdgcn_cosf(rev - floorf(rev));
}

// scalar pow-16 with folded prefactor: y = SF*(1+cos(theta-theta_t)); y^16
static __device__ __forceinline__ float pow16v(float cv, float sv,
                                               float tc, float ts, float sf) {
    float y = fmaf(cv, tc, fmaf(sv, ts, sf));
    y = y * y; y = y * y; y = y * y; y = y * y;
    return y;
}

// ---------------------------------------------------------------------------
// desc_kernel: one block per atom (blocks 0..NATC-1); blocks >= NATC run the
// former prep_kernel (W1/W2 bf16 B-frag pack + out = NATC*b3).
// R9 delta vs proven R8: phase-4 bf16 converts (64 per lane) go through
// hardware v_cvt_pk_bf16_f32 (1 op / 2 values) instead of plain-C f2bf
// (software RNE sequence risk, ~4 ops each). pbr build = R2's exact proven
// code; afr chain stays scalar f32, only the final converts are paired.
// Everything else VERBATIM R8. LDS = 19520 B.
// ---------------------------------------------------------------------------
__global__ __launch_bounds__(256, 4) void desc_kernel(
    const float* __restrict__ pos,
    const float* __restrict__ spe,
    const float* __restrict__ theta_s,
    const float* __restrict__ kn_rad,
    const int* __restrict__ nidx,
    ushort* __restrict__ descb,
    const float* __restrict__ W1, const float* __restrict__ W2,
    const float* __restrict__ b3,
    ushort* __restrict__ W1p, ushort* __restrict__ W2p,
    float* __restrict__ out)
{
    constexpr float RC = 5.0f;
    constexpr float SF = 0.52213689121f;   // 2^(-15/16); SF^16 = 2^(1-16)

    const int tid = threadIdx.x;

    // ---- prep tail blocks (former prep_kernel) ----
    if (blockIdx.x >= NATC) {
        const int gid = (blockIdx.x - NATC) * 256 + tid;   // 0..5119
        if (gid == 0) out[0] = (float)NATC * b3[0];
        if (gid < 4608) {                                  // W1: 18 ks * 4 nt * 64 l
            const int l = gid & 63, ntks = gid >> 6;
            const int nt = ntks & 3, ks = ntks >> 2;
            const int qq = l >> 4, cc = l & 15;
            ushort pk[8];
            #pragma unroll
            for (int jj = 0; jj < 8; ++jj)
                pk[jj] = (ushort)f2bf(W1[(ks * 32 + qq * 8 + jj) * 64 + nt * 16 + cc]);
            #pragma unroll
            for (int jj = 0; jj < 8; ++jj) W1p[gid * 8 + jj] = pk[jj];
        } else {                                           // W2: 2 ks * 4 nt * 64 l
            const int g = gid - 4608;
            const int l = g & 63, ntks = g >> 6;
            const int nt = ntks & 3, ks = ntks >> 2;
            const int qq = l >> 4, cc = l & 15;
            ushort pk[8];
            #pragma unroll
            for (int jj = 0; jj < 8; ++jj)
                pk[jj] = (ushort)f2bf(W2[(ks * 32 + qq * 8 + jj) * 64 + nt * 16 + cc]);
            #pragma unroll
            for (int jj = 0; jj < 8; ++jj) W2p[g * 8 + jj] = pk[jj];
        }
        return;
    }

    __shared__ __attribute__((aligned(16))) float Pt[64 * 36];    // P^T, pad 36
    __shared__ __attribute__((aligned(16))) float cosP[32 * 36];
    __shared__ __attribute__((aligned(16))) float sinP[32 * 36];
    __shared__ float thc[16];            // {SF*cos(th_t), SF*sin(th_t)} x 8
    __shared__ float ux[32], uy[32], uz[32];
    __shared__ __attribute__((aligned(16))) float ses[32 * 5];

    const int i = blockIdx.x;

    // --- phase 0: bond geometry + Bessel (all lanes, j = tid&31, registers) ---
    const int j0 = tid & 31;
    float g0, g1, g2, g3, g4, g5, g6, g7;   // this lane's 8 Bessel values
    {
        const int n = nidx[i * NNC + j0];
        const float pix = pos[i * 3 + 0], piy = pos[i * 3 + 1], piz = pos[i * 3 + 2];
        const float dx = pos[n * 3 + 0] - pix;
        const float dy = pos[n * 3 + 1] - piy;
        const float dz = pos[n * 3 + 2] - piz;
        const float r = sqrtf(dx * dx + dy * dy + dz * dz) + 1e-8f;
        const float inv = 1.0f / r;
        // fc = 0.5*(cos(pi*r/RC)+1) for r<RC; rev = r/(2*RC)
        const float fcc = hw_cos_rev(r * (0.5f / RC));
        const float fc = (r < RC) ? 0.5f * (fcc + 1.0f) : 0.0f;
        const float rb = sqrtf(2.0f / RC) * inv * fc;
        // x = (pi/RC)*kn*r  ->  rev = kn*r/(2*RC)
        const float rev = (0.5f / RC) * kn_rad[0] * r;
        const float rf  = rev - floorf(rev);
        const float s1   = __builtin_amdgcn_sinf(rf);
        const float cosx = __builtin_amdgcn_cosf(rf);
        const float c2x = 2.0f * cosx;
        const float c4x = fmaf(c2x, c2x, -2.0f);     // 2*cos(2x)
        // parity-split step-2 Chebyshev: s_{k+2} = c4x*s_k - s_{k-2}
        if (tid & 128) {            // even indices 2,4,...,16
            const float s2  = c2x * s1;
            const float s4  = c4x * s2;              // s0 = 0
            const float s6  = fmaf(c4x, s4,  -s2);
            const float s8  = fmaf(c4x, s6,  -s4);
            const float s10 = fmaf(c4x, s8,  -s6);
            const float s12 = fmaf(c4x, s10, -s8);
            const float s14 = fmaf(c4x, s12, -s10);
            const float s16 = fmaf(c4x, s14, -s12);
            g0 = rb * s2;  g1 = rb * s4;  g2 = rb * s6;  g3 = rb * s8;
            g4 = rb * s10; g5 = rb * s12; g6 = rb * s14; g7 = rb * s16;
        } else {                    // odd indices 1,3,...,15
            const float s3  = fmaf(c4x, s1, s1);     // s_{-1} = -s1
            const float s5  = fmaf(c4x, s3,  -s1);
            const float s7  = fmaf(c4x, s5,  -s3);
            const float s9  = fmaf(c4x, s7,  -s5);
            const float s11 = fmaf(c4x, s9,  -s7);
            const float s13 = fmaf(c4x, s11, -s9);
            const float s15 = fmaf(c4x, s13, -s11);
            g0 = rb * s1;  g1 = rb * s3;  g2 = rb * s5;  g3 = rb * s7;
            g4 = rb * s9;  g5 = rb * s11; g6 = rb * s13; g7 = rb * s15;
        }
        if (tid < NNC) {
            ux[j0] = dx * inv; uy[j0] = dy * inv; uz[j0] = dz * inv;
            #pragma unroll
            for (int m = 0; m < NEMBC; ++m)
                ses[j0 * 5 + m] = spe[n * NEMBC + m] * spe[i * NEMBC + m];
        }
        if (tid >= 64 && tid < 72) {
            const int t = tid - 64;
            const float th = theta_s[t];   // precise trig: pow-16 amplifies
            thc[2 * t]     = SF * cosf(th);
            thc[2 * t + 1] = SF * sinf(th);
        }
    }
    __syncthreads();

    // --- phase 2: P^T (stride 36) + cos/sin planes (stride 36) ---
    {
        const int base = tid >> 5;                  // 0..7
        const float se = ses[j0 * 5 + (base & 3)];
        Pt[(base +  0) * 36 + j0] = g0 * se;
        Pt[(base +  8) * 36 + j0] = g1 * se;
        Pt[(base + 16) * 36 + j0] = g2 * se;
        Pt[(base + 24) * 36 + j0] = g3 * se;
        Pt[(base + 32) * 36 + j0] = g4 * se;
        Pt[(base + 40) * 36 + j0] = g5 * se;
        Pt[(base + 48) * 36 + j0] = g6 * se;
        Pt[(base + 56) * 36 + j0] = g7 * se;
    }
    #pragma unroll
    for (int k = 0; k < 4; ++k) {
        const int e = tid + k * 256;
        const int j = e & 31, kk = e >> 5;          // symmetric: c(j,kk)=c(kk,j)
        float cv = ux[j] * ux[kk] + uy[j] * uy[kk] + uz[j] * uz[kk];
        cv = fminf(fmaxf(cv, -1.0f + 1e-6f), 1.0f - 1e-6f);
        cosP[kk * 36 + j] = cv;
        sinP[kk * 36 + j] = sqrtf(fmaxf(1.0f - cv * cv, 0.0f));
    }
    __syncthreads();

    // --- phase 3: radial descriptor (wave 0, 64 lanes) ---
    if (tid < 64) {
        const f32x4* pr = (const f32x4*)&Pt[tid * 36];
        float s = 0.0f;
        #pragma unroll
        for (int kb = 0; kb < 8; ++kb) {
            const f32x4 v = pr[kb];
            s += v[0]; s += v[1]; s += v[2]; s += v[3];
        }
        descb[(size_t)i * FEATC + tid] = (ushort)f2bf(s);
    }

    // --- phase 4: MFMA contraction per theta; ZERO in-loop LDS reads ---
    const int w = tid >> 6, l = tid & 63;
    const int q = l >> 4, c = l & 15;

    // Hoist cos/sin A-rows (kk = c and 16+c, cols q*8..q*8+7) -> named scalars
    float cA[8], sA[8], cB[8], sB[8];
    {
        const f32x4* p0 = (const f32x4*)&cosP[c * 36 + q * 8];
        const f32x4 a0 = p0[0], a1 = p0[1];
        cA[0]=a0[0]; cA[1]=a0[1]; cA[2]=a0[2]; cA[3]=a0[3];
        cA[4]=a1[0]; cA[5]=a1[1]; cA[6]=a1[2]; cA[7]=a1[3];
        const f32x4* p1 = (const f32x4*)&sinP[c * 36 + q * 8];
        const f32x4 b0 = p1[0], b1 = p1[1];
        sA[0]=b0[0]; sA[1]=b0[1]; sA[2]=b0[2]; sA[3]=b0[3];
        sA[4]=b1[0]; sA[5]=b1[1]; sA[6]=b1[2]; sA[7]=b1[3];
        const f32x4* p2 = (const f32x4*)&cosP[(16 + c) * 36 + q * 8];
        const f32x4 c0 = p2[0], c1 = p2[1];
        cB[0]=c0[0]; cB[1]=c0[1]; cB[2]=c0[2]; cB[3]=c0[3];
        cB[4]=c1[0]; cB[5]=c1[1]; cB[6]=c1[2]; cB[7]=c1[3];
        const f32x4* p3 = (const f32x4*)&sinP[(16 + c) * 36 + q * 8];
        const f32x4 d0 = p3[0], d1 = p3[1];
        sB[0]=d0[0]; sB[1]=d0[1]; sB[2]=d0[2]; sB[3]=d0[3];
        sB[4]=d1[0]; sB[5]=d1[1]; sB[6]=d1[2]; sB[7]=d1[3];
    }

    // Hoist epilogue P^T slices -> named scalars (unrolled constant indices)
    float pvv[4][2][4];
    #pragma unroll
    for (int nt = 0; nt < 4; ++nt)
        #pragma unroll
        for (int mt = 0; mt < 2; ++mt) {
            const f32x4 t = *(const f32x4*)&Pt[(nt * 16 + c) * 36 + mt * 16 + q * 4];
            pvv[nt][mt][0] = t[0]; pvv[nt][mt][1] = t[1];
            pvv[nt][mt][2] = t[2]; pvv[nt][mt][3] = t[3];
        }

    // bf16 B-fragments from Pt rows (theta-independent), HW paired converts
    // (exact R2-proven pattern: cvt_pk asm, hoisted across the theta loop)
    short8 pbr[4];
    #pragma unroll
    for (int nt = 0; nt < 4; ++nt) {
        const f32x4* prow = (const f32x4*)&Pt[(nt * 16 + c) * 36 + q * 8];
        const f32x4 p0 = prow[0], p1 = prow[1];
        union { short8 s8; int i4[4]; } u;
        u.i4[0] = cvt_pk_bf16(p0[0], p0[1]);
        u.i4[1] = cvt_pk_bf16(p0[2], p0[3]);
        u.i4[2] = cvt_pk_bf16(p1[0], p1[1]);
        u.i4[3] = cvt_pk_bf16(p1[2], p1[3]);
        pbr[nt] = u.s8;
    }

    #pragma unroll
    for (int tt = 0; tt < 2; ++tt) {
        const int t = w + tt * 4;
        const float tc = thc[2 * t], ts = thc[2 * t + 1];

        // A-fragments: scalar f32 pow-16 chain, HW paired converts at the end
        short8 afr0, afr1;
        {
            union { short8 s8; int i4[4]; } u;
            u.i4[0] = cvt_pk_bf16(pow16v(cA[0], sA[0], tc, ts, SF),
                                  pow16v(cA[1], sA[1], tc, ts, SF));
            u.i4[1] = cvt_pk_bf16(pow16v(cA[2], sA[2], tc, ts, SF),
                                  pow16v(cA[3], sA[3], tc, ts, SF));
            u.i4[2] = cvt_pk_bf16(pow16v(cA[4], sA[4], tc, ts, SF),
                                  pow16v(cA[5], sA[5], tc, ts, SF));
            u.i4[3] = cvt_pk_bf16(pow16v(cA[6], sA[6], tc, ts, SF),
                                  pow16v(cA[7], sA[7], tc, ts, SF));
            afr0 = u.s8;
            u.i4[0] = cvt_pk_bf16(pow16v(cB[0], sB[0], tc, ts, SF),
                                  pow16v(cB[1], sB[1], tc, ts, SF));
            u.i4[1] = cvt_pk_bf16(pow16v(cB[2], sB[2], tc, ts, SF),
                                  pow16v(cB[3], sB[3], tc, ts, SF));
            u.i4[2] = cvt_pk_bf16(pow16v(cB[4], sB[4], tc, ts, SF),
                                  pow16v(cB[5], sB[5], tc, ts, SF));
            u.i4[3] = cvt_pk_bf16(pow16v(cB[6], sB[6], tc, ts, SF),
                                  pow16v(cB[7], sB[7], tc, ts, SF));
            afr1 = u.s8;
        }

        float ptv[4];
        #pragma unroll
        for (int nt = 0; nt < 4; ++nt) {
            f32x4 acc0 = (f32x4){0.0f, 0.0f, 0.0f, 0.0f};
            f32x4 acc1 = (f32x4){0.0f, 0.0f, 0.0f, 0.0f};
            acc0 = __builtin_amdgcn_mfma_f32_16x16x32_bf16(afr0, pbr[nt], acc0, 0, 0, 0);
            acc1 = __builtin_amdgcn_mfma_f32_16x16x32_bf16(afr1, pbr[nt], acc1, 0, 0, 0);
            // scalar dot replicating the packed lo/hi summation order exactly
            float slo = 0.0f, shi = 0.0f;
            slo = fmaf(acc0[0], pvv[nt][0][0], slo); shi = fmaf(acc0[1], pvv[nt][0][1], shi);
            slo = fmaf(acc0[2], pvv[nt][0][2], slo); shi = fmaf(acc0[3], pvv[nt][0][3], shi);
            slo = fmaf(acc1[0], pvv[nt][1][0], slo); shi = fmaf(acc1[1], pvv[nt][1][1], shi);
            slo = fmaf(acc1[2], pvv[nt][1][2], slo); shi = fmaf(acc1[3], pvv[nt][1][3], shi);
            float s = slo + shi;
            s += __shfl_xor(s, 16, 64);
            s += __shfl_xor(s, 32, 64);
            ptv[nt] = s;
        }
        const float v = (q == 0) ? ptv[0] : (q == 1) ? ptv[1] : (q == 2) ? ptv[2] : ptv[3];
        descb[(size_t)i * FEATC + 64 + t * 64 + l] = (ushort)f2bf(v);
    }
}

// ---------------------------------------------------------------------------
// mlp_kernel: 16 atoms/block (grid 626), wave w = n-tile. UNCHANGED (proven).
// ---------------------------------------------------------------------------
__global__ __launch_bounds__(256) void mlp_kernel(
    const ushort* __restrict__ descb,
    const ushort* __restrict__ W1p, const float* __restrict__ b1,
    const ushort* __restrict__ W2p, const float* __restrict__ b2,
    const float* __restrict__ W3,
    float* __restrict__ out)
{
    __shared__ __attribute__((aligned(16))) ushort H1b[16 * 72];
    __shared__ float red[4];

    const int tid = threadIdx.x;
    const int w = tid >> 6, l = tid & 63;
    const int q = l >> 4, c = l & 15;
    const int a0 = blockIdx.x * 16;

    f32x4 acc = (f32x4){0.0f, 0.0f, 0.0f, 0.0f};

    #pragma unroll 6
    for (int ks = 0; ks < 18; ++ks) {
        const short8 b   = *(const short8*)&W1p[((ks * 4 + w) * 64 + l) * 8];
        const short8 afr = *(const short8*)&descb[(size_t)(a0 + c) * FEATC + ks * 32 + q * 8];
        acc = __builtin_amdgcn_mfma_f32_16x16x32_bf16(afr, b, acc, 0, 0, 0);
    }

    const float b1v = b1[w * 16 + c];
    #pragma unroll
    for (int r = 0; r < 4; ++r)
        H1b[(q * 4 + r) * 72 + w * 16 + c] = (ushort)f2bf(tanhf(acc[r] + b1v));
    __syncthreads();

    f32x4 acc2 = (f32x4){0.0f, 0.0f, 0.0f, 0.0f};
    #pragma unroll
    for (int ks = 0; ks < 2; ++ks) {
        const short8 b   = *(const short8*)&W2p[((ks * 4 + w) * 64 + l) * 8];
        const short8 afr = *(const short8*)&H1b[c * 72 + ks * 32 + q * 8];
        acc2 = __builtin_amdgcn_mfma_f32_16x16x32_bf16(afr, b, acc2, 0, 0, 0);
    }

    const float b2v = b2[w * 16 + c];
    const float w3v = W3[w * 16 + c];
    float s = 0.0f;
    #pragma unroll
    for (int r = 0; r < 4; ++r) {
        const int a = a0 + q * 4 + r;
        if (a < NATC) s += tanhf(acc2[r] + b2v) * w3v;
    }
    #pragma unroll
    for (int off = 1; off <= 32; off <<= 1)
        s += __shfl_xor(s, off, 64);
    if (l == 0) red[w] = s;
    __syncthreads();
    if (tid == 0)
        atomicAdd(out, red[0] + red[1] + red[2] + red[3]);
}

extern "C" void kernel_launch(void* const* d_in, const int* in_sizes, int n_in,
                              void* d_out, int out_size, void* d_ws, size_t ws_size,
                              hipStream_t stream)
{
    const float* pos   = (const float*)d_in[0];
    const float* spe   = (const float*)d_in[1];
    const float* theta = (const float*)d_in[2];
    const float* kn    = (const float*)d_in[3];
    const float* W1    = (const float*)d_in[4];
    const float* b1    = (const float*)d_in[5];
    const float* W2    = (const float*)d_in[6];
    const float* b2    = (const float*)d_in[7];
    const float* W3    = (const float*)d_in[8];
    const float* b3    = (const float*)d_in[9];
    const int*   nidx  = (const int*)d_in[10];
    float* out = (float*)d_out;

    // workspace layout (bytes): descb [NATP*576 u16] | W1p [36864 u16] | W2p [4096 u16]
    ushort* descb = (ushort*)d_ws;
    ushort* W1p   = (ushort*)((char*)d_ws + (size_t)NATP * FEATC * 2);   // 11,538,432
    ushort* W2p   = W1p + 4608 * 8;

    desc_kernel<<<NATC + 20, 256, 0, stream>>>(pos, spe, theta, kn, nidx, descb,
                                               W1, W2, b3, W1p, W2p, out);
    mlp_kernel<<<(NATC + 15) / 16, 256, 0, stream>>>(descb, W1p, b1, W2p, b2, W3, out);
}

// Round 10
// 126.140 us; speedup vs baseline: 1.0386x; 1.0386x over previous
//
#include <hip/hip_runtime.h>
#include <hip/hip_bf16.h>

#define NATC 10000
#define NATP 10016          // padded atom count for MFMA m-tiles
#define NNC 32
#define RSNC 16
#define THETANC 8
#define NEMBC 4
#define FEATC 576

typedef __attribute__((ext_vector_type(8))) short short8;  // 8 bf16 (4 VGPRs)
typedef __attribute__((ext_vector_type(4))) float f32x4;

static __device__ __forceinline__ short f2bf(float x) {
    union { __hip_bfloat16 h; short s; } u;
    u.h = __float2bfloat16(x);
    return u.s;
}

// HW trig: v_sin/v_cos take REVOLUTIONS; reduce exactly via floor.
static __device__ __forceinline__ float hw_cos_rev(float rev) {
    return __builtin_amdgcn_cosf(rev - floorf(rev));
}

// ---------------------------------------------------------------------------
// desc_kernel: one block per atom (blocks 0..NATC-1); blocks >= NATC run the
// former prep_kernel (W1/W2 bf16 B-frag pack + out = NATC*b3).
// R10 = R8 VERBATIM (empirical optimum: 127.77 us total, desc 43.5 us).
// R9 falsified the cvt_pk-asm hypothesis: plain f2bf already lowers to the
// hardware convert, and inline asm (opaque to the scheduler) cost +12 VGPR,
// -21 occupancy, +27% duration. Inline-asm axis closed in all forms:
//   R3/R4 (hoisted tuples x asm) = miscompile; R9 (scalar asm) = -27%.
// Structure summary:
//  - phase 0: all-lane redundant Bessel via parity-split step-2 Chebyshev,
//    HW v_sin/v_cos (revolutions); named-scalar registers (rule-#20 safe).
//  - phase 2: P^T (stride 36) from registers; cos/sin planes (stride 36).
//  - phase 4: ALL theta-invariant LDS reads (cos/sin A-rows, epilogue P^T
//    slices, pbr B-frags) hoisted ONCE into named scalars; zero in-loop
//    ds_reads; plain-C pow-16 chain; scalar epilogue replicating the packed
//    lo/hi summation order (bit-identical, absmax 0.0).
// LDS = 19520 B; VGPR 32; ~65% occupancy; VALUBusy ~79% (VALU-issue bound).
// ---------------------------------------------------------------------------
__global__ __launch_bounds__(256, 4) void desc_kernel(
    const float* __restrict__ pos,
    const float* __restrict__ spe,
    const float* __restrict__ theta_s,
    const float* __restrict__ kn_rad,
    const int* __restrict__ nidx,
    ushort* __restrict__ descb,
    const float* __restrict__ W1, const float* __restrict__ W2,
    const float* __restrict__ b3,
    ushort* __restrict__ W1p, ushort* __restrict__ W2p,
    float* __restrict__ out)
{
    constexpr float RC = 5.0f;
    constexpr float SF = 0.52213689121f;   // 2^(-15/16); SF^16 = 2^(1-16)

    const int tid = threadIdx.x;

    // ---- prep tail blocks (former prep_kernel) ----
    if (blockIdx.x >= NATC) {
        const int gid = (blockIdx.x - NATC) * 256 + tid;   // 0..5119
        if (gid == 0) out[0] = (float)NATC * b3[0];
        if (gid < 4608) {                                  // W1: 18 ks * 4 nt * 64 l
            const int l = gid & 63, ntks = gid >> 6;
            const int nt = ntks & 3, ks = ntks >> 2;
            const int qq = l >> 4, cc = l & 15;
            ushort pk[8];
            #pragma unroll
            for (int jj = 0; jj < 8; ++jj)
                pk[jj] = (ushort)f2bf(W1[(ks * 32 + qq * 8 + jj) * 64 + nt * 16 + cc]);
            #pragma unroll
            for (int jj = 0; jj < 8; ++jj) W1p[gid * 8 + jj] = pk[jj];
        } else {                                           // W2: 2 ks * 4 nt * 64 l
            const int g = gid - 4608;
            const int l = g & 63, ntks = g >> 6;
            const int nt = ntks & 3, ks = ntks >> 2;
            const int qq = l >> 4, cc = l & 15;
            ushort pk[8];
            #pragma unroll
            for (int jj = 0; jj < 8; ++jj)
                pk[jj] = (ushort)f2bf(W2[(ks * 32 + qq * 8 + jj) * 64 + nt * 16 + cc]);
            #pragma unroll
            for (int jj = 0; jj < 8; ++jj) W2p[g * 8 + jj] = pk[jj];
        }
        return;
    }

    __shared__ __attribute__((aligned(16))) float Pt[64 * 36];    // P^T, pad 36
    __shared__ __attribute__((aligned(16))) float cosP[32 * 36];
    __shared__ __attribute__((aligned(16))) float sinP[32 * 36];
    __shared__ float thc[16];            // {SF*cos(th_t), SF*sin(th_t)} x 8
    __shared__ float ux[32], uy[32], uz[32];
    __shared__ __attribute__((aligned(16))) float ses[32 * 5];

    const int i = blockIdx.x;

    // --- phase 0: bond geometry + Bessel (all lanes, j = tid&31, registers) ---
    const int j0 = tid & 31;
    float g0, g1, g2, g3, g4, g5, g6, g7;   // this lane's 8 Bessel values
    {
        const int n = nidx[i * NNC + j0];
        const float pix = pos[i * 3 + 0], piy = pos[i * 3 + 1], piz = pos[i * 3 + 2];
        const float dx = pos[n * 3 + 0] - pix;
        const float dy = pos[n * 3 + 1] - piy;
        const float dz = pos[n * 3 + 2] - piz;
        const float r = sqrtf(dx * dx + dy * dy + dz * dz) + 1e-8f;
        const float inv = 1.0f / r;
        // fc = 0.5*(cos(pi*r/RC)+1) for r<RC; rev = r/(2*RC)
        const float fcc = hw_cos_rev(r * (0.5f / RC));
        const float fc = (r < RC) ? 0.5f * (fcc + 1.0f) : 0.0f;
        const float rb = sqrtf(2.0f / RC) * inv * fc;
        // x = (pi/RC)*kn*r  ->  rev = kn*r/(2*RC)
        const float rev = (0.5f / RC) * kn_rad[0] * r;
        const float rf  = rev - floorf(rev);
        const float s1   = __builtin_amdgcn_sinf(rf);
        const float cosx = __builtin_amdgcn_cosf(rf);
        const float c2x = 2.0f * cosx;
        const float c4x = fmaf(c2x, c2x, -2.0f);     // 2*cos(2x)
        // parity-split step-2 Chebyshev: s_{k+2} = c4x*s_k - s_{k-2}
        if (tid & 128) {            // even indices 2,4,...,16
            const float s2  = c2x * s1;
            const float s4  = c4x * s2;              // s0 = 0
            const float s6  = fmaf(c4x, s4,  -s2);
            const float s8  = fmaf(c4x, s6,  -s4);
            const float s10 = fmaf(c4x, s8,  -s6);
            const float s12 = fmaf(c4x, s10, -s8);
            const float s14 = fmaf(c4x, s12, -s10);
            const float s16 = fmaf(c4x, s14, -s12);
            g0 = rb * s2;  g1 = rb * s4;  g2 = rb * s6;  g3 = rb * s8;
            g4 = rb * s10; g5 = rb * s12; g6 = rb * s14; g7 = rb * s16;
        } else {                    // odd indices 1,3,...,15
            const float s3  = fmaf(c4x, s1, s1);     // s_{-1} = -s1
            const float s5  = fmaf(c4x, s3,  -s1);
            const float s7  = fmaf(c4x, s5,  -s3);
            const float s9  = fmaf(c4x, s7,  -s5);
            const float s11 = fmaf(c4x, s9,  -s7);
            const float s13 = fmaf(c4x, s11, -s9);
            const float s15 = fmaf(c4x, s13, -s11);
            g0 = rb * s1;  g1 = rb * s3;  g2 = rb * s5;  g3 = rb * s7;
            g4 = rb * s9;  g5 = rb * s11; g6 = rb * s13; g7 = rb * s15;
        }
        if (tid < NNC) {
            ux[j0] = dx * inv; uy[j0] = dy * inv; uz[j0] = dz * inv;
            #pragma unroll
            for (int m = 0; m < NEMBC; ++m)
                ses[j0 * 5 + m] = spe[n * NEMBC + m] * spe[i * NEMBC + m];
        }
        if (tid >= 64 && tid < 72) {
            const int t = tid - 64;
            const float th = theta_s[t];   // precise trig: pow-16 amplifies
            thc[2 * t]     = SF * cosf(th);
            thc[2 * t + 1] = SF * sinf(th);
        }
    }
    __syncthreads();

    // --- phase 2: P^T (stride 36) + cos/sin planes (stride 36) ---
    {
        const int base = tid >> 5;                  // 0..7
        const float se = ses[j0 * 5 + (base & 3)];
        Pt[(base +  0) * 36 + j0] = g0 * se;
        Pt[(base +  8) * 36 + j0] = g1 * se;
        Pt[(base + 16) * 36 + j0] = g2 * se;
        Pt[(base + 24) * 36 + j0] = g3 * se;
        Pt[(base + 32) * 36 + j0] = g4 * se;
        Pt[(base + 40) * 36 + j0] = g5 * se;
        Pt[(base + 48) * 36 + j0] = g6 * se;
        Pt[(base + 56) * 36 + j0] = g7 * se;
    }
    #pragma unroll
    for (int k = 0; k < 4; ++k) {
        const int e = tid + k * 256;
        const int j = e & 31, kk = e >> 5;          // symmetric: c(j,kk)=c(kk,j)
        float cv = ux[j] * ux[kk] + uy[j] * uy[kk] + uz[j] * uz[kk];
        cv = fminf(fmaxf(cv, -1.0f + 1e-6f), 1.0f - 1e-6f);
        cosP[kk * 36 + j] = cv;
        sinP[kk * 36 + j] = sqrtf(fmaxf(1.0f - cv * cv, 0.0f));
    }
    __syncthreads();

    // --- phase 3: radial descriptor (wave 0, 64 lanes) ---
    if (tid < 64) {
        const f32x4* pr = (const f32x4*)&Pt[tid * 36];
        float s = 0.0f;
        #pragma unroll
        for (int kb = 0; kb < 8; ++kb) {
            const f32x4 v = pr[kb];
            s += v[0]; s += v[1]; s += v[2]; s += v[3];
        }
        descb[(size_t)i * FEATC + tid] = (ushort)f2bf(s);
    }

    // --- phase 4: MFMA contraction per theta; ZERO in-loop LDS reads ---
    const int w = tid >> 6, l = tid & 63;
    const int q = l >> 4, c = l & 15;

    // Hoist cos/sin A-rows (kk = c and 16+c, cols q*8..q*8+7) -> named scalars
    float cA[8], sA[8], cB[8], sB[8];
    {
        const f32x4* p0 = (const f32x4*)&cosP[c * 36 + q * 8];
        const f32x4 a0 = p0[0], a1 = p0[1];
        cA[0]=a0[0]; cA[1]=a0[1]; cA[2]=a0[2]; cA[3]=a0[3];
        cA[4]=a1[0]; cA[5]=a1[1]; cA[6]=a1[2]; cA[7]=a1[3];
        const f32x4* p1 = (const f32x4*)&sinP[c * 36 + q * 8];
        const f32x4 b0 = p1[0], b1 = p1[1];
        sA[0]=b0[0]; sA[1]=b0[1]; sA[2]=b0[2]; sA[3]=b0[3];
        sA[4]=b1[0]; sA[5]=b1[1]; sA[6]=b1[2]; sA[7]=b1[3];
        const f32x4* p2 = (const f32x4*)&cosP[(16 + c) * 36 + q * 8];
        const f32x4 c0 = p2[0], c1 = p2[1];
        cB[0]=c0[0]; cB[1]=c0[1]; cB[2]=c0[2]; cB[3]=c0[3];
        cB[4]=c1[0]; cB[5]=c1[1]; cB[6]=c1[2]; cB[7]=c1[3];
        const f32x4* p3 = (const f32x4*)&sinP[(16 + c) * 36 + q * 8];
        const f32x4 d0 = p3[0], d1 = p3[1];
        sB[0]=d0[0]; sB[1]=d0[1]; sB[2]=d0[2]; sB[3]=d0[3];
        sB[4]=d1[0]; sB[5]=d1[1]; sB[6]=d1[2]; sB[7]=d1[3];
    }

    // Hoist epilogue P^T slices -> named scalars (unrolled constant indices)
    float pvv[4][2][4];
    #pragma unroll
    for (int nt = 0; nt < 4; ++nt)
        #pragma unroll
        for (int mt = 0; mt < 2; ++mt) {
            const f32x4 t = *(const f32x4*)&Pt[(nt * 16 + c) * 36 + mt * 16 + q * 4];
            pvv[nt][mt][0] = t[0]; pvv[nt][mt][1] = t[1];
            pvv[nt][mt][2] = t[2]; pvv[nt][mt][3] = t[3];
        }

    // bf16 B-fragments from Pt rows (theta-independent), plain-C converts
    short8 pbr[4];
    #pragma unroll
    for (int nt = 0; nt < 4; ++nt) {
        const f32x4* prow = (const f32x4*)&Pt[(nt * 16 + c) * 36 + q * 8];
        const f32x4 p0 = prow[0], p1 = prow[1];
        pbr[nt][0] = f2bf(p0[0]); pbr[nt][1] = f2bf(p0[1]);
        pbr[nt][2] = f2bf(p0[2]); pbr[nt][3] = f2bf(p0[3]);
        pbr[nt][4] = f2bf(p1[0]); pbr[nt][5] = f2bf(p1[1]);
        pbr[nt][6] = f2bf(p1[2]); pbr[nt][7] = f2bf(p1[3]);
    }

    #pragma unroll
    for (int tt = 0; tt < 2; ++tt) {
        const int t = w + tt * 4;
        const float tc = thc[2 * t], ts = thc[2 * t + 1];

        // A-fragments: plain-C pow-16 chain (same op sequence as packed ver.)
        short8 afr0, afr1;
        #pragma unroll
        for (int jj = 0; jj < 8; ++jj) {
            float y = fmaf(cA[jj], tc, fmaf(sA[jj], ts, SF));
            y = y * y; y = y * y; y = y * y; y = y * y;
            afr0[jj] = f2bf(y);
        }
        #pragma unroll
        for (int jj = 0; jj < 8; ++jj) {
            float y = fmaf(cB[jj], tc, fmaf(sB[jj], ts, SF));
            y = y * y; y = y * y; y = y * y; y = y * y;
            afr1[jj] = f2bf(y);
        }

        float ptv[4];
        #pragma unroll
        for (int nt = 0; nt < 4; ++nt) {
            f32x4 acc0 = (f32x4){0.0f, 0.0f, 0.0f, 0.0f};
            f32x4 acc1 = (f32x4){0.0f, 0.0f, 0.0f, 0.0f};
            acc0 = __builtin_amdgcn_mfma_f32_16x16x32_bf16(afr0, pbr[nt], acc0, 0, 0, 0);
            acc1 = __builtin_amdgcn_mfma_f32_16x16x32_bf16(afr1, pbr[nt], acc1, 0, 0, 0);
            // scalar dot replicating the packed lo/hi summation order exactly
            float slo = 0.0f, shi = 0.0f;
            slo = fmaf(acc0[0], pvv[nt][0][0], slo); shi = fmaf(acc0[1], pvv[nt][0][1], shi);
            slo = fmaf(acc0[2], pvv[nt][0][2], slo); shi = fmaf(acc0[3], pvv[nt][0][3], shi);
            slo = fmaf(acc1[0], pvv[nt][1][0], slo); shi = fmaf(acc1[1], pvv[nt][1][1], shi);
            slo = fmaf(acc1[2], pvv[nt][1][2], slo); shi = fmaf(acc1[3], pvv[nt][1][3], shi);
            float s = slo + shi;
            s += __shfl_xor(s, 16, 64);
            s += __shfl_xor(s, 32, 64);
            ptv[nt] = s;
        }
        const float v = (q == 0) ? ptv[0] : (q == 1) ? ptv[1] : (q == 2) ? ptv[2] : ptv[3];
        descb[(size_t)i * FEATC + 64 + t * 64 + l] = (ushort)f2bf(v);
    }
}

// ---------------------------------------------------------------------------
// mlp_kernel: 16 atoms/block (grid 626), wave w = n-tile. UNCHANGED (proven).
// ---------------------------------------------------------------------------
__global__ __launch_bounds__(256) void mlp_kernel(
    const ushort* __restrict__ descb,
    const ushort* __restrict__ W1p, const float* __restrict__ b1,
    const ushort* __restrict__ W2p, const float* __restrict__ b2,
    const float* __restrict__ W3,
    float* __restrict__ out)
{
    __shared__ __attribute__((aligned(16))) ushort H1b[16 * 72];
    __shared__ float red[4];

    const int tid = threadIdx.x;
    const int w = tid >> 6, l = tid & 63;
    const int q = l >> 4, c = l & 15;
    const int a0 = blockIdx.x * 16;

    f32x4 acc = (f32x4){0.0f, 0.0f, 0.0f, 0.0f};

    #pragma unroll 6
    for (int ks = 0; ks < 18; ++ks) {
        const short8 b   = *(const short8*)&W1p[((ks * 4 + w) * 64 + l) * 8];
        const short8 afr = *(const short8*)&descb[(size_t)(a0 + c) * FEATC + ks * 32 + q * 8];
        acc = __builtin_amdgcn_mfma_f32_16x16x32_bf16(afr, b, acc, 0, 0, 0);
    }

    const float b1v = b1[w * 16 + c];
    #pragma unroll
    for (int r = 0; r < 4; ++r)
        H1b[(q * 4 + r) * 72 + w * 16 + c] = (ushort)f2bf(tanhf(acc[r] + b1v));
    __syncthreads();

    f32x4 acc2 = (f32x4){0.0f, 0.0f, 0.0f, 0.0f};
    #pragma unroll
    for (int ks = 0; ks < 2; ++ks) {
        const short8 b   = *(const short8*)&W2p[((ks * 4 + w) * 64 + l) * 8];
        const short8 afr = *(const short8*)&H1b[c * 72 + ks * 32 + q * 8];
        acc2 = __builtin_amdgcn_mfma_f32_16x16x32_bf16(afr, b, acc2, 0, 0, 0);
    }

    const float b2v = b2[w * 16 + c];
    const float w3v = W3[w * 16 + c];
    float s = 0.0f;
    #pragma unroll
    for (int r = 0; r < 4; ++r) {
        const int a = a0 + q * 4 + r;
        if (a < NATC) s += tanhf(acc2[r] + b2v) * w3v;
    }
    #pragma unroll
    for (int off = 1; off <= 32; off <<= 1)
        s += __shfl_xor(s, off, 64);
    if (l == 0) red[w] = s;
    __syncthreads();
    if (tid == 0)
        atomicAdd(out, red[0] + red[1] + red[2] + red[3]);
}

extern "C" void kernel_launch(void* const* d_in, const int* in_sizes, int n_in,
                              void* d_out, int out_size, void* d_ws, size_t ws_size,
                              hipStream_t stream)
{
    const float* pos   = (const float*)d_in[0];
    const float* spe   = (const float*)d_in[1];
    const float* theta = (const float*)d_in[2];
    const float* kn    = (const float*)d_in[3];
    const float* W1    = (const float*)d_in[4];
    const float* b1    = (const float*)d_in[5];
    const float* W2    = (const float*)d_in[6];
    const float* b2    = (const float*)d_in[7];
    const float* W3    = (const float*)d_in[8];
    const float* b3    = (const float*)d_in[9];
    const int*   nidx  = (const int*)d_in[10];
    float* out = (float*)d_out;

    // workspace layout (bytes): descb [NATP*576 u16] | W1p [36864 u16] | W2p [4096 u16]
    ushort* descb = (ushort*)d_ws;
    ushort* W1p   = (ushort*)((char*)d_ws + (size_t)NATP * FEATC * 2);   // 11,538,432
    ushort* W2p   = W1p + 4608 * 8;

    desc_kernel<<<NATC + 20, 256, 0, stream>>>(pos, spe, theta, kn, nidx, descb,
                                               W1, W2, b3, W1p, W2p, out);
    mlp_kernel<<<(NATC + 15) / 16, 256, 0, stream>>>(descb, W1p, b1, W2p, b2, W3, out);
}